// Round 3
// baseline (24785.995 us; speedup 1.0000x reference)
//
#include <hip/hip_runtime.h>
#include <math.h>

// Problem constants
#define BQ 256   // batch
#define NN 1024  // nodes
#define EE 256   // embed
#define HH 8     // heads
#define DHD 32   // head dim
#define TS 64    // decode steps
#define SCALE 0.17677669529663687f  // 1/sqrt(32)
#define CLIPC 10.0f

// ---------------------------------------------------------------------------
// One-time projections: [B*N,256] @ [256,768]. cols 0..255 -> K (transposed
// out [B,H,D,N]), 256..511 -> V (out [B,H,N,D]), 512..767 -> pointer keys
// (transposed out [B,E,N]). 64x64 tile, BK=16, 4x4 per thread. (round-2)
// ---------------------------------------------------------------------------
__global__ __launch_bounds__(256) void proj_kernel(
    const float* __restrict__ x, const float* __restrict__ Wqkv,
    const float* __restrict__ bqkv, const float* __restrict__ Wpk,
    const float* __restrict__ bpk, float* __restrict__ kbuf,
    float* __restrict__ vbuf, float* __restrict__ kpbuf)
{
    __shared__ float As[16][68];
    __shared__ float Ws[16][68];
    int tid = threadIdx.x;
    int r0 = blockIdx.x * 64;
    int cb = blockIdx.y * 64;
    int lm = tid >> 2, lk = (tid & 3) * 4;
    int wk = tid >> 4, wc = (tid & 15) * 4;
    int ty = tid >> 4, tx = tid & 15;
    int m0 = ty * 4, c0 = tx * 4;
    float acc[4][4] = {};
    for (int kk = 0; kk < 256; kk += 16) {
        float4 av = *(const float4*)(x + (size_t)(r0 + lm) * EE + kk + lk);
        As[lk + 0][lm] = av.x; As[lk + 1][lm] = av.y;
        As[lk + 2][lm] = av.z; As[lk + 3][lm] = av.w;
        float4 wv;
        if (cb < 512) wv = *(const float4*)(Wqkv + (size_t)(kk + wk) * 768 + 256 + cb + wc);
        else          wv = *(const float4*)(Wpk  + (size_t)(kk + wk) * EE + (cb - 512) + wc);
        *(float4*)&Ws[wk][wc] = wv;
        __syncthreads();
        #pragma unroll
        for (int k = 0; k < 16; k++) {
            float4 a = *(const float4*)&As[k][m0];
            float4 w = *(const float4*)&Ws[k][c0];
            acc[0][0] += a.x * w.x; acc[0][1] += a.x * w.y; acc[0][2] += a.x * w.z; acc[0][3] += a.x * w.w;
            acc[1][0] += a.y * w.x; acc[1][1] += a.y * w.y; acc[1][2] += a.y * w.z; acc[1][3] += a.y * w.w;
            acc[2][0] += a.z * w.x; acc[2][1] += a.z * w.y; acc[2][2] += a.z * w.z; acc[2][3] += a.z * w.w;
            acc[3][0] += a.w * w.x; acc[3][1] += a.w * w.y; acc[3][2] += a.w * w.z; acc[3][3] += a.w * w.w;
        }
        __syncthreads();
    }
    int bb = r0 >> 10;
    int nbase = (r0 & 1023) + m0;
    int region = cb >> 8;
    if (region == 0) {
        #pragma unroll
        for (int j = 0; j < 4; j++) {
            int c = cb + c0 + j;
            float bias = bqkv[256 + c];
            int h = c >> 5, d = c & 31;
            float4 o = make_float4(acc[0][j] + bias, acc[1][j] + bias,
                                   acc[2][j] + bias, acc[3][j] + bias);
            *(float4*)(kbuf + (((size_t)bb * HH + h) * DHD + d) * NN + nbase) = o;
        }
    } else if (region == 1) {
        int c2 = cb + c0 - 256;
        int h = c2 >> 5, d0 = c2 & 31;
        #pragma unroll
        for (int i = 0; i < 4; i++) {
            float4 o = make_float4(acc[i][0] + bqkv[512 + c2 + 0],
                                   acc[i][1] + bqkv[512 + c2 + 1],
                                   acc[i][2] + bqkv[512 + c2 + 2],
                                   acc[i][3] + bqkv[512 + c2 + 3]);
            *(float4*)(vbuf + (((size_t)bb * HH + h) * NN + nbase + i) * DHD + d0) = o;
        }
    } else {
        #pragma unroll
        for (int j = 0; j < 4; j++) {
            int e = cb + c0 + j - 512;
            float bias = bpk[e];
            float4 o = make_float4(acc[0][j] + bias, acc[1][j] + bias,
                                   acc[2][j] + bias, acc[3][j] + bias);
            *(float4*)(kpbuf + ((size_t)bb * EE + e) * NN + nbase) = o;
        }
    }
}

// ---------------------------------------------------------------------------
// Persistent decoder: one block per batch element, all 64 steps in-kernel.
// All per-batch state lives in LDS. Every fp op is kept bitwise-identical to
// the round-2 step kernels (GEMVs verbatim on threads<256; attention as 4
// sequential head-pairs, each 256-thread group running the round-2 attn code;
// pointer/argmax/update verbatim).
// ---------------------------------------------------------------------------
__global__ __launch_bounds__(512) void decoder_kernel(
    const float* __restrict__ x, const float* __restrict__ demand,
    const float* __restrict__ cap0,
    const float* __restrict__ Wc, const float* __restrict__ bc,
    const float* __restrict__ Wqkv, const float* __restrict__ bqkv,
    const float* __restrict__ Wo, const float* __restrict__ bo,
    const float* __restrict__ Wpq, const float* __restrict__ bpq,
    const float* __restrict__ kbuf, const float* __restrict__ vbuf,
    const float* __restrict__ kpbuf,
    float* __restrict__ probs_out, float* __restrict__ route_out)
{
    int b = blockIdx.x;
    int tid = threadIdx.x;     // 0..511
    int g = tid >> 8;          // head-pair group (0/1)
    int t8 = tid & 255;        // tid within group

    __shared__ float p2[2][NN];            // attn exp weights, per group
    __shared__ float dem_s[NN];
    __shared__ unsigned char vis_s[NN];
    __shared__ unsigned char mbit[NN];
    __shared__ float sum_embed[EE];
    __shared__ float cvec[516];
    __shared__ float ve_s[EE];
    __shared__ float q_s[EE];
    __shared__ float ctx_s[EE];
    __shared__ float co_s[EE];
    __shared__ float qp_s[EE];
    __shared__ float qs2[2][DHD];
    __shared__ float red2[2][4];
    __shared__ float vred2[2][8][33];
    __shared__ float smx2[2], ssum2[2];
    __shared__ float red1[4];
    __shared__ int   redi1[4];
    __shared__ float s_mx1, s_sum1;
    __shared__ float s_cap, s_cnt;
    __shared__ int   s_cur, s_node;

    // ---- init: demand, visited, scalars, sum_embed (identical to init_kernel)
    if (tid < 256)
        *(float4*)&dem_s[tid * 4] = *(const float4*)(demand + b * NN + tid * 4);
    vis_s[tid] = 0; vis_s[tid + 512] = 0;
    if (tid == 0) { s_cap = cap0[b]; s_cnt = 1024.0f; s_cur = 0; }
    if (tid < 256) {
        const float* xb = x + (size_t)b * NN * EE + tid;
        float s = 0.f;
        #pragma unroll 8
        for (int n = 0; n < NN; n++) s += xb[(size_t)n * EE];
        sum_embed[tid] = s;
    }
    __syncthreads();

    for (int t = 0; t < TS; t++) {
        // ---- S1: cvec = [mean, sel, cap]
        if (tid < 256) {
            cvec[tid] = sum_embed[tid] / s_cnt;
            cvec[256 + tid] = x[((size_t)b * NN + s_cur) * EE + tid];
        }
        if (tid == 0) cvec[512] = s_cap;
        __syncthreads();
        // ---- S2: ve = cvec@Wc + bc  (round-2 verbatim)
        if (tid < 256) {
            float acc = bc[tid];
            #pragma unroll 4
            for (int i = 0; i < 513; i++) acc += cvec[i] * Wc[i * EE + tid];
            ve_s[tid] = acc;
        }
        __syncthreads();
        // ---- S3: q = ve@Wq + bq  (round-2 verbatim)
        if (tid < 256) {
            float q = bqkv[tid];
            #pragma unroll 4
            for (int i = 0; i < EE; i++) q += ve_s[i] * Wqkv[i * 768 + tid];
            q_s[tid] = q;
        }
        // ---- S4: masks for this step (same values as round-2 inline masks)
        {
            float capv = s_cap; int cur = s_cur;
            int n0 = tid * 2;
            bool m0 = (vis_s[n0] != 0) || (dem_s[n0] > capv);
            bool m1 = (vis_s[n0 + 1] != 0) || (dem_s[n0 + 1] > capv);
            if (n0 == 0 && cur == 0) m0 = true;
            mbit[n0] = m0 ? 1 : 0; mbit[n0 + 1] = m1 ? 1 : 0;
            int allm = __syncthreads_and((m0 && m1) ? 1 : 0);
            if (allm && tid == 0) mbit[0] = 0;
        }
        __syncthreads();

        // ---- attention: 4 head-pairs; group g handles head hp*2+g with the
        //      round-2 attn_kernel code on its 256 threads.
        for (int hp = 0; hp < 4; hp++) {
            int h = hp * 2 + g;
            if (t8 < DHD) qs2[g][t8] = q_s[h * DHD + t8];
            __syncthreads();
            const float* kb = kbuf + (size_t)(b * HH + h) * DHD * NN;
            int n0 = t8 * 4;
            float4 s4 = {0.f, 0.f, 0.f, 0.f};
            #pragma unroll 8
            for (int d = 0; d < DHD; d++) {
                float4 kv = *(const float4*)(kb + (d << 10) + n0);
                float qd = qs2[g][d];
                s4.x = fmaf(qd, kv.x, s4.x);
                s4.y = fmaf(qd, kv.y, s4.y);
                s4.z = fmaf(qd, kv.z, s4.z);
                s4.w = fmaf(qd, kv.w, s4.w);
            }
            float sc[4] = {s4.x * SCALE, s4.y * SCALE, s4.z * SCALE, s4.w * SCALE};
            bool m[4] = {mbit[n0] != 0, mbit[n0 + 1] != 0,
                         mbit[n0 + 2] != 0, mbit[n0 + 3] != 0};
            float lmax = -INFINITY;
            #pragma unroll
            for (int i = 0; i < 4; i++) {
                sc[i] = m[i] ? -INFINITY : sc[i];
                lmax = fmaxf(lmax, sc[i]);
            }
            #pragma unroll
            for (int o = 32; o > 0; o >>= 1) lmax = fmaxf(lmax, __shfl_down(lmax, o));
            if ((t8 & 63) == 0) red2[g][t8 >> 6] = lmax;
            __syncthreads();
            if (t8 == 0) smx2[g] = fmaxf(fmaxf(red2[g][0], red2[g][1]),
                                         fmaxf(red2[g][2], red2[g][3]));
            __syncthreads();
            float mx = smx2[g];
            float4 e4;
            e4.x = (sc[0] == -INFINITY) ? 0.f : expf(sc[0] - mx);
            e4.y = (sc[1] == -INFINITY) ? 0.f : expf(sc[1] - mx);
            e4.z = (sc[2] == -INFINITY) ? 0.f : expf(sc[2] - mx);
            e4.w = (sc[3] == -INFINITY) ? 0.f : expf(sc[3] - mx);
            *(float4*)&p2[g][n0] = e4;
            float lsum = e4.x + e4.y + e4.z + e4.w;
            #pragma unroll
            for (int o = 32; o > 0; o >>= 1) lsum += __shfl_down(lsum, o);
            if ((t8 & 63) == 0) red2[g][t8 >> 6] = lsum;
            __syncthreads();
            if (t8 == 0) ssum2[g] = red2[g][0] + red2[g][1] + red2[g][2] + red2[g][3];
            __syncthreads();
            // ctx numerators: 8 chunks x 128 nodes (round-2 verbatim)
            int d = t8 & 31, chunk = t8 >> 5;
            const float* vb = vbuf + (size_t)(b * HH + h) * NN * DHD;
            float acc = 0.f;
            int nbase = chunk * 128;
            #pragma unroll 4
            for (int n = nbase; n < nbase + 128; n++)
                acc += p2[g][n] * vb[(size_t)n * DHD + d];
            vred2[g][chunk][d] = acc;
            __syncthreads();
            if (t8 < DHD) {
                float s = 0.f;
                #pragma unroll
                for (int c = 0; c < 8; c++) s += vred2[g][c][t8];
                ctx_s[h * DHD + t8] = s / ssum2[g];
            }
            __syncthreads();
        }

        // ---- S8: co = ctx@Wo + bo  (round-2 verbatim)
        if (tid < 256) {
            float a = bo[tid];
            #pragma unroll 4
            for (int i = 0; i < EE; i++) a += ctx_s[i] * Wo[i * EE + tid];
            co_s[tid] = a;
        }
        __syncthreads();
        // ---- S9: qp = co@Wpq + bpq  (round-2 verbatim)
        if (tid < 256) {
            float a = bpq[tid];
            #pragma unroll 4
            for (int i = 0; i < EE; i++) a += co_s[i] * Wpq[i * EE + tid];
            qp_s[tid] = a;
        }
        __syncthreads();

        // ---- S10/S11: pointer logits, softmax, probs, argmax, update
        //      (round-2 prob_kernel verbatim on threads<256)
        float u[4]; float pe[4]; int n0p = t8 * 4;
        if (tid < 256) {
            const float* kpb = kpbuf + (size_t)b * EE * NN;
            float4 s4 = {0.f, 0.f, 0.f, 0.f};
            #pragma unroll 8
            for (int e = 0; e < EE; e++) {
                float4 kv = *(const float4*)(kpb + (e << 10) + n0p);
                float qe = qp_s[e];
                s4.x = fmaf(qe, kv.x, s4.x);
                s4.y = fmaf(qe, kv.y, s4.y);
                s4.z = fmaf(qe, kv.z, s4.z);
                s4.w = fmaf(qe, kv.w, s4.w);
            }
            u[0] = CLIPC * tanhf(s4.x); u[1] = CLIPC * tanhf(s4.y);
            u[2] = CLIPC * tanhf(s4.z); u[3] = CLIPC * tanhf(s4.w);
            bool m[4] = {mbit[n0p] != 0, mbit[n0p + 1] != 0,
                         mbit[n0p + 2] != 0, mbit[n0p + 3] != 0};
            float lmax = -INFINITY;
            #pragma unroll
            for (int i = 0; i < 4; i++) {
                u[i] = m[i] ? -INFINITY : u[i];
                lmax = fmaxf(lmax, u[i]);
            }
            #pragma unroll
            for (int o = 32; o > 0; o >>= 1) lmax = fmaxf(lmax, __shfl_down(lmax, o));
            if ((tid & 63) == 0) red1[tid >> 6] = lmax;
        }
        __syncthreads();
        if (tid == 0) s_mx1 = fmaxf(fmaxf(red1[0], red1[1]), fmaxf(red1[2], red1[3]));
        __syncthreads();
        if (tid < 256) {
            float mx = s_mx1;
            float lsum = 0.f;
            #pragma unroll
            for (int i = 0; i < 4; i++) {
                pe[i] = (u[i] == -INFINITY) ? 0.f : expf(u[i] - mx);
                lsum += pe[i];
            }
            #pragma unroll
            for (int o = 32; o > 0; o >>= 1) lsum += __shfl_down(lsum, o);
            if ((tid & 63) == 0) red1[tid >> 6] = lsum;
        }
        __syncthreads();
        if (tid == 0) s_sum1 = red1[0] + red1[1] + red1[2] + red1[3];
        __syncthreads();
        if (tid < 256) {
            float sm = s_sum1;
            float4 pv4;
            float* pv = (float*)&pv4;
            float bu = -1.f; int bn = 1 << 30;
            #pragma unroll
            for (int i = 0; i < 4; i++) {
                pv[i] = pe[i] / sm;
                int n = n0p + i;
                if (pv[i] > bu || (pv[i] == bu && n < bn)) { bu = pv[i]; bn = n; }
            }
            *(float4*)(probs_out + (size_t)t * BQ * NN + (size_t)b * NN + n0p) = pv4;
            #pragma unroll
            for (int o = 32; o > 0; o >>= 1) {
                float ou = __shfl_down(bu, o);
                int   on = __shfl_down(bn, o);
                if (ou > bu || (ou == bu && on < bn)) { bu = ou; bn = on; }
            }
            if ((tid & 63) == 0) { red1[tid >> 6] = bu; redi1[tid >> 6] = bn; }
        }
        __syncthreads();
        if (tid == 0) {
            float vv = red1[0]; int nd = redi1[0];
            for (int w = 1; w < 4; w++)
                if (red1[w] > vv || (red1[w] == vv && redi1[w] < nd)) { vv = red1[w]; nd = redi1[w]; }
            s_node = nd;
            route_out[t * BQ + b] = (float)nd;
            s_cap = s_cap - dem_s[nd];
            s_cur = nd;
            if (nd != 0) {
                vis_s[nd] = 1;
                s_cnt -= 1.f;
            }
        }
        __syncthreads();
        if (tid < 256) {
            int node = s_node;
            if (node != 0)
                sum_embed[tid] -= x[((size_t)b * NN + node) * EE + tid];
        }
        __syncthreads();
    }
}

// ---------------------------------------------------------------------------
extern "C" void kernel_launch(void* const* d_in, const int* in_sizes, int n_in,
                              void* d_out, int out_size, void* d_ws, size_t ws_size,
                              hipStream_t stream) {
    const float* x      = (const float*)d_in[0];
    const float* demand = (const float*)d_in[1];
    const float* cap0   = (const float*)d_in[2];
    const float* Wc     = (const float*)d_in[3];
    const float* bc     = (const float*)d_in[4];
    const float* Wqkv   = (const float*)d_in[5];
    const float* bqkv   = (const float*)d_in[6];
    const float* Wo     = (const float*)d_in[7];
    const float* bo     = (const float*)d_in[8];
    const float* Wpq    = (const float*)d_in[9];
    const float* bpq    = (const float*)d_in[10];
    const float* Wpk    = (const float*)d_in[11];
    const float* bpk    = (const float*)d_in[12];
    float* out = (float*)d_out;

    float* kbuf  = (float*)d_ws;          // [B,H,D,N]
    float* vbuf  = kbuf + 67108864;       // [B,H,N,D]
    float* kpbuf = vbuf + 67108864;       // [B,E,N]

    float* probs_out = out;                          // [T,B,N]
    float* route_out = out + (size_t)TS * BQ * NN;   // [T,B]

    hipLaunchKernelGGL(proj_kernel, dim3(4096, 12), dim3(256), 0, stream,
                       x, Wqkv, bqkv, Wpk, bpk, kbuf, vbuf, kpbuf);
    hipLaunchKernelGGL(decoder_kernel, dim3(BQ), dim3(512), 0, stream,
                       x, demand, cap0, Wc, bc, Wqkv, bqkv, Wo, bo, Wpq, bpq,
                       kbuf, vbuf, kpbuf, probs_out, route_out);
}